// Round 1
// baseline (398.396 us; speedup 1.0000x reference)
//
#include <hip/hip_runtime.h>
#include <stdint.h>

#define N_ROWS 65536
#define CIN 256
#define COUT 128

typedef __bf16 bf16x8 __attribute__((ext_vector_type(8)));
typedef float f32x4 __attribute__((ext_vector_type(4)));
typedef unsigned short u16;
typedef unsigned int u32;

__device__ __forceinline__ float truncbf(float f) {
  u32 x = __builtin_bit_cast(u32, f) & 0xFFFF0000u;
  return __builtin_bit_cast(float, x);
}
// {hi16(b), hi16(a)} -> (bf(b)<<16)|bf(a)
__device__ __forceinline__ u32 packbf(float a, float b) {
  return __builtin_amdgcn_perm(__builtin_bit_cast(u32, b),
                               __builtin_bit_cast(u32, a), 0x07060302u);
}

__device__ __forceinline__ void async_ld16(const void* g, void* l) {
  __builtin_amdgcn_global_load_lds((const __attribute__((address_space(1))) u32*)g,
                                   (__attribute__((address_space(3))) u32*)l,
                                   16, 0, 0);
}

// ---------------------------------------------------------------------------
// Kernel 1: partial Gram over 256-row slices + per-block colsum + xb emit.
// 256 blocks x 512 thr -> 1 block/CU.
// xT layout: [np(16 row-pairs)][260 ch] packed bf16 pairs, pad 4.
//  - writes: one ds_write_b128 per thread per half -> conflict-free
//  - frag reads: 4x b32, banks (16q + r + 4s) -> exactly 2-way (free)
// ---------------------------------------------------------------------------
template <bool EMIT_XB>
__global__ __launch_bounds__(512, 2) void gram_partial(const float* __restrict__ x,
                                                       float* __restrict__ part,
                                                       float* __restrict__ csb,
                                                       u32* __restrict__ xb) {
  __shared__ u32 xT[16 * 260];        // 16.25KB
  __shared__ float cs_s[8][256];      // 8KB
  const int tid = threadIdx.x, lane = tid & 63;
  const int w = tid >> 6;
  const int wm = w >> 2, wn = w & 3;  // wave tile: 128(m) x 64(n) of G
  const int q = lane >> 4, r = lane & 15;
  const int row0 = blockIdx.x * 256;
  const int cq = tid & 63;            // channel quad: channels 4cq..4cq+3
  const int np2 = tid >> 6;           // 0..7: handles row-pairs np2, np2+8

  f32x4 acc[8][4];
  #pragma unroll
  for (int i = 0; i < 8; ++i)
    #pragma unroll
    for (int j = 0; j < 4; ++j) acc[i][j] = (f32x4){0.f, 0.f, 0.f, 0.f};
  f32x4 cs = (f32x4){0.f, 0.f, 0.f, 0.f};

  for (int ch = 0; ch < 8; ++ch) {
    const int r0 = row0 + ch * 32;
    const int nA = r0 + np2 * 2;          // rows nA, nA+1
    const int nB = r0 + (np2 + 8) * 2;    // rows nB, nB+1
    f32x4 a0 = *(const f32x4*)&x[(size_t)nA * CIN + 4 * cq];
    f32x4 a1 = *(const f32x4*)&x[(size_t)(nA + 1) * CIN + 4 * cq];
    f32x4 b0 = *(const f32x4*)&x[(size_t)nB * CIN + 4 * cq];
    f32x4 b1 = *(const f32x4*)&x[(size_t)(nB + 1) * CIN + 4 * cq];

    union { u32 d[4]; uint4 v; } pA, pB;
    #pragma unroll
    for (int j = 0; j < 4; ++j) {
      pA.d[j] = packbf(a0[j], a1[j]);
      pB.d[j] = packbf(b0[j], b1[j]);
      cs[j] += truncbf(a0[j]) + truncbf(a1[j]) + truncbf(b0[j]) + truncbf(b1[j]);
    }
    *(uint4*)&xT[np2 * 260 + 4 * cq] = pA.v;
    *(uint4*)&xT[(np2 + 8) * 260 + 4 * cq] = pB.v;
    if (EMIT_XB) {
      uint2 e;
      e.x = packbf(a0[0], a0[1]); e.y = packbf(a0[2], a0[3]);
      *(uint2*)&xb[(size_t)nA * 128 + 2 * cq] = e;
      e.x = packbf(a1[0], a1[1]); e.y = packbf(a1[2], a1[3]);
      *(uint2*)&xb[(size_t)(nA + 1) * 128 + 2 * cq] = e;
      e.x = packbf(b0[0], b0[1]); e.y = packbf(b0[2], b0[3]);
      *(uint2*)&xb[(size_t)nB * 128 + 2 * cq] = e;
      e.x = packbf(b1[0], b1[1]); e.y = packbf(b1[2], b1[3]);
      *(uint2*)&xb[(size_t)(nB + 1) * 128 + 2 * cq] = e;
    }
    __syncthreads();
    bf16x8 af[8], bfr[4];
    #pragma unroll
    for (int mt = 0; mt < 8; ++mt) {
      int c = wm * 128 + mt * 16 + r;
      union { u32 d[4]; bf16x8 v; } t;
      #pragma unroll
      for (int s = 0; s < 4; ++s) t.d[s] = xT[(4 * q + s) * 260 + c];
      af[mt] = t.v;
    }
    #pragma unroll
    for (int nt = 0; nt < 4; ++nt) {
      int c = wn * 64 + nt * 16 + r;
      union { u32 d[4]; bf16x8 v; } t;
      #pragma unroll
      for (int s = 0; s < 4; ++s) t.d[s] = xT[(4 * q + s) * 260 + c];
      bfr[nt] = t.v;
    }
    #pragma unroll
    for (int mt = 0; mt < 8; ++mt)
      #pragma unroll
      for (int nt = 0; nt < 4; ++nt)
        acc[mt][nt] = __builtin_amdgcn_mfma_f32_16x16x32_bf16(af[mt], bfr[nt], acc[mt][nt], 0, 0, 0);
    __syncthreads();
  }

  float* pb = part + (size_t)blockIdx.x * 65536;
  #pragma unroll
  for (int mt = 0; mt < 8; ++mt)
    #pragma unroll
    for (int nt = 0; nt < 4; ++nt)
      #pragma unroll
      for (int i = 0; i < 4; ++i) {
        int row = wm * 128 + mt * 16 + q * 4 + i;
        int col = wn * 64 + nt * 16 + r;
        pb[row * 256 + col] = acc[mt][nt][i];
      }

  *(f32x4*)&cs_s[np2][4 * cq] = cs;
  __syncthreads();
  if (tid < 256) {
    float s = 0.f;
    #pragma unroll
    for (int p = 0; p < 8; ++p) s += cs_s[p][tid];
    csb[(size_t)blockIdx.x * 256 + tid] = s;
  }
}

// ---------------------------------------------------------------------------
// Kernel 2: reduce 256 partial Grams -> G. 1024 blocks x 256 thr (4/CU),
// float4 loads, 16-way split of the 256 partials per block.
// ---------------------------------------------------------------------------
__global__ __launch_bounds__(256) void gram_reduce(const float* __restrict__ part,
                                                   float* __restrict__ G) {
  __shared__ float red[16][64];
  const int t = threadIdx.x;
  const int fi = t & 15, grp = t >> 4;
  const int g0 = blockIdx.x * 64;
  f32x4 a = (f32x4){0.f, 0.f, 0.f, 0.f};
  const float* p = part + (size_t)(grp * 16) * 65536 + g0 + fi * 4;
  #pragma unroll
  for (int b = 0; b < 16; ++b) a += *(const f32x4*)(p + (size_t)b * 65536);
  *(f32x4*)&red[grp][fi * 4] = a;
  __syncthreads();
  if (t < 64) {
    float s = 0.f;
    #pragma unroll
    for (int gq = 0; gq < 16; ++gq) s += red[gq][t];
    G[g0 + t] = s;
  }
}

// ---------------------------------------------------------------------------
// Kernel 3: BN scale/bias per channel d from quadratic form.
// ---------------------------------------------------------------------------
__global__ __launch_bounds__(256) void stats_kernel(const float* __restrict__ G,
                                                    const float* __restrict__ csb,
                                                    const float* __restrict__ W,
                                                    const float* __restrict__ gamma,
                                                    const float* __restrict__ beta,
                                                    float* __restrict__ scale,
                                                    float* __restrict__ bias) {
  const int d = blockIdx.x;
  const int t = threadIdx.x;
  __shared__ float wv[256][8];
  __shared__ float rr[16];
  float cst = 0.f;
  for (int b = 0; b < 256; ++b) cst += csb[b * 256 + t];
  float wt[8];
  #pragma unroll
  for (int k = 0; k < 8; ++k) wt[k] = truncbf(W[((size_t)k * CIN + t) * COUT + d]);
  #pragma unroll
  for (int k = 0; k < 8; ++k) wv[t][k] = wt[k];
  __syncthreads();

  float q = 0.f;
  for (int j = 0; j < 256; ++j) {
    float g = G[j * 256 + t];
    float dot = 0.f;
    #pragma unroll
    for (int k = 0; k < 8; ++k) dot += wv[j][k] * wt[k];
    q += g * dot;
  }
  float wsum = 0.f;
  #pragma unroll
  for (int k = 0; k < 8; ++k) wsum += wt[k];
  float m = cst * wsum;

  #pragma unroll
  for (int off = 32; off; off >>= 1) {
    q += __shfl_down(q, off, 64);
    m += __shfl_down(m, off, 64);
  }
  int wid = t >> 6;
  if ((t & 63) == 0) { rr[wid] = q; rr[wid + 8] = m; }
  __syncthreads();
  if (t == 0) {
    float qt = rr[0] + rr[1] + rr[2] + rr[3];
    float mn = rr[8] + rr[9] + rr[10] + rr[11];
    const float invM = 1.f / 524288.f;
    float mean = mn * invM;
    float var = qt * invM - mean * mean;
    float s = gamma[d] * rsqrtf(var + 1e-5f);
    scale[d] = s;
    bias[d] = beta[d] - mean * s;
  }
}

// ---------------------------------------------------------------------------
// Kernel 4: W fp32 [k][c][d] -> Wt bf16 [(k*8+cb)][d][ci]
// ---------------------------------------------------------------------------
__global__ void wtrans_kernel(const float* __restrict__ W, u16* __restrict__ Wt) {
  __shared__ u16 tile[32][128];
  const int blk = blockIdx.x, t = threadIdx.x;
  const int k = blk >> 3, cb = blk & 7;
  #pragma unroll
  for (int i = 0; i < 4; ++i) {
    int u = t + i * 256;
    int ci = u >> 5, d4 = (u & 31) * 4;
    float4 f = *(const float4*)&W[((size_t)k * CIN + cb * 32 + ci) * COUT + d4];
    uint2 p; p.x = packbf(f.x, f.y); p.y = packbf(f.z, f.w);
    *(uint2*)&tile[ci][d4] = p;
  }
  __syncthreads();
  #pragma unroll
  for (int i = 0; i < 2; ++i) {
    int v = t + i * 256;
    int d = v >> 2, c0 = (v & 3) * 8;
    union { u16 s[8]; uint4 u4; } p;
    #pragma unroll
    for (int j = 0; j < 8; ++j) p.s[j] = tile[c0 + j][d];
    *(uint4*)&Wt[((size_t)blk * 128 + d) * 32 + c0] = p.u4;
  }
}

// ---------------------------------------------------------------------------
// Kernel 5 (main path): GEMM from bf16 xb, all 8 k-offsets per block.
// 512 blocks x 256 thr. A-tile 128x256 bf16 = 64KB LDS staged ONCE.
// XOR swizzle (seg ^= (row>>1)&3) applied on the *global source* address
// (LDS dest must stay linear for global_load_lds) and mirrored on the
// ds_read side -> conflict-free b128 A-fragment reads (was 4-way).
// ---------------------------------------------------------------------------
__global__ __launch_bounds__(256, 2) void gemm_xb(const u16* __restrict__ xb,
                                                  const u16* __restrict__ Wt,
                                                  const float* __restrict__ scale,
                                                  const float* __restrict__ bias,
                                                  float* __restrict__ out) {
  __shared__ u16 As[32768];           // 64KB: [cb][row][32] bf16, seg-swizzled
  const int tid = threadIdx.x, lane = tid & 63;
  const int w = tid >> 6, wr = w >> 1, wc = w & 1;
  const int q = lane >> 4, r = lane & 15;
  const int m0 = blockIdx.x * 128;

  #pragma unroll
  for (int i = 0; i < 16; ++i) {
    int u = tid + i * 256;            // 4096 units of 16B
    int cb = u >> 9, row = (u >> 2) & 127;
    int sseg = (u ^ (u >> 3)) & 3;    // seg ^ ((row>>1)&3)
    const u16* g = xb + (size_t)(m0 + row) * CIN + cb * 32 + sseg * 8;
    async_ld16(g, As + (size_t)u * 8);
  }

  float sv[4], bv[4];
  #pragma unroll
  for (int nt = 0; nt < 4; ++nt) {
    int col = wc * 64 + nt * 16 + r;
    sv[nt] = scale[col]; bv[nt] = bias[col];
  }

  const int boff = (wc * 64 + r) * 32 + q * 8;
  const int sw = (q ^ ((r >> 1) & 3)) * 8;   // swizzled seg offset for reads
  bf16x8 bcur[4], bnext[4];
  #pragma unroll
  for (int nt = 0; nt < 4; ++nt)
    bcur[nt] = *(const bf16x8*)&Wt[boff + nt * 512];

  __syncthreads();                    // drains the A staging too

  int j = 0;                          // j = k*8+cb
  for (int k = 0; k < 8; ++k) {
    f32x4 acc[4][4];
    #pragma unroll
    for (int i = 0; i < 4; ++i)
      #pragma unroll
      for (int jj = 0; jj < 4; ++jj) acc[i][jj] = (f32x4){0.f, 0.f, 0.f, 0.f};

    #pragma unroll
    for (int cb = 0; cb < 8; ++cb) {
      if (j < 63) {
        #pragma unroll
        for (int nt = 0; nt < 4; ++nt)
          bnext[nt] = *(const bf16x8*)&Wt[(size_t)(j + 1) * 4096 + boff + nt * 512];
      }
      bf16x8 af[4];
      #pragma unroll
      for (int mt = 0; mt < 4; ++mt)
        af[mt] = *(const bf16x8*)&As[((cb * 128) + wr * 64 + mt * 16 + r) * 32 + sw];
      #pragma unroll
      for (int mt = 0; mt < 4; ++mt)
        #pragma unroll
        for (int nt = 0; nt < 4; ++nt)
          acc[mt][nt] = __builtin_amdgcn_mfma_f32_16x16x32_bf16(af[mt], bcur[nt], acc[mt][nt], 0, 0, 0);
      if (j < 63) {
        #pragma unroll
        for (int nt = 0; nt < 4; ++nt) bcur[nt] = bnext[nt];
      }
      ++j;
    }

    const size_t obase = (size_t)k * N_ROWS + m0;
    #pragma unroll
    for (int mt = 0; mt < 4; ++mt)
      #pragma unroll
      for (int nt = 0; nt < 4; ++nt)
        #pragma unroll
        for (int i = 0; i < 4; ++i) {
          int grow = wr * 64 + mt * 16 + q * 4 + i;
          int col = wc * 64 + nt * 16 + r;
          float y = acc[mt][nt][i] * sv[nt] + bv[nt];
          y = y > 0.f ? y : 0.f;
          out[(obase + grow) * COUT + col] = y;
        }
  }
}

// ---------------------------------------------------------------------------
// Kernel 5 (fallback, round-2 proven): GEMM from fp32 x, one k per block.
// ---------------------------------------------------------------------------
__global__ __launch_bounds__(256, 2) void gemm_fp32(const float* __restrict__ x,
                                                    const u16* __restrict__ Wt,
                                                    const float* __restrict__ scale,
                                                    const float* __restrict__ bias,
                                                    float* __restrict__ out) {
  __shared__ float Asf[4096];
  const int tid = threadIdx.x, lane = tid & 63;
  const int w = tid >> 6, wr = w >> 1, wc = w & 1;
  const int q = lane >> 4, r = lane & 15;
  const int k = blockIdx.x & 7;
  const int m0 = (blockIdx.x >> 3) * 128;

  const u16* wbase = Wt + (size_t)k * 8 * 4096;
  const int boff = (wc * 64 + r) * 32 + q * 8;

  bf16x8 bcur[4], bnext[4];
  #pragma unroll
  for (int nt = 0; nt < 4; ++nt)
    bcur[nt] = *(const bf16x8*)&wbase[boff + nt * 512];

  f32x4 acc[4][4];
  #pragma unroll
  for (int i = 0; i < 4; ++i)
    #pragma unroll
    for (int j = 0; j < 4; ++j) acc[i][j] = (f32x4){0.f, 0.f, 0.f, 0.f};

  for (int cb = 0; cb < 8; ++cb) {
    #pragma unroll
    for (int i = 0; i < 4; ++i) {
      int u = tid + i * 256;
      int row = u >> 3;
      int s = (u & 7) ^ (row & 7);
      const float* g = x + (size_t)(m0 + row) * CIN + cb * 32 + s * 4;
      async_ld16(g, Asf + (w * 64 + i * 256) * 4);
    }
    if (cb < 7) {
      #pragma unroll
      for (int nt = 0; nt < 4; ++nt)
        bnext[nt] = *(const bf16x8*)&wbase[(cb + 1) * 4096 + boff + nt * 512];
    }
    __syncthreads();
    bf16x8 af[4];
    #pragma unroll
    for (int mt = 0; mt < 4; ++mt) {
      int row = wr * 64 + mt * 16 + r;
      union { u32 d[4]; bf16x8 v; } t;
      #pragma unroll
      for (int b = 0; b < 2; ++b) {
        int unit = row * 8 + ((2 * q + b) ^ (row & 7));
        float4 f = *(const float4*)&Asf[unit * 4];
        t.d[b * 2 + 0] = packbf(f.x, f.y);
        t.d[b * 2 + 1] = packbf(f.z, f.w);
      }
      af[mt] = t.v;
    }
    #pragma unroll
    for (int mt = 0; mt < 4; ++mt)
      #pragma unroll
      for (int nt = 0; nt < 4; ++nt)
        acc[mt][nt] = __builtin_amdgcn_mfma_f32_16x16x32_bf16(af[mt], bcur[nt], acc[mt][nt], 0, 0, 0);
    __syncthreads();
    if (cb < 7) {
      #pragma unroll
      for (int nt = 0; nt < 4; ++nt) bcur[nt] = bnext[nt];
    }
  }

  float sv[4], bv[4];
  #pragma unroll
  for (int nt = 0; nt < 4; ++nt) {
    int col = wc * 64 + nt * 16 + r;
    sv[nt] = scale[col]; bv[nt] = bias[col];
  }
  const size_t obase = (size_t)k * N_ROWS + m0;
  #pragma unroll
  for (int mt = 0; mt < 4; ++mt)
    #pragma unroll
    for (int nt = 0; nt < 4; ++nt)
      #pragma unroll
      for (int i = 0; i < 4; ++i) {
        int grow = wr * 64 + mt * 16 + q * 4 + i;
        int col = wc * 64 + nt * 16 + r;
        float y = acc[mt][nt][i] * sv[nt] + bv[nt];
        y = y > 0.f ? y : 0.f;
        out[(obase + grow) * COUT + col] = y;
      }
}

extern "C" void kernel_launch(void* const* d_in, const int* in_sizes, int n_in,
                              void* d_out, int out_size, void* d_ws, size_t ws_size,
                              hipStream_t stream) {
  const float* x = (const float*)d_in[0];
  const float* W = (const float*)d_in[1];
  const float* gamma = (const float*)d_in[2];
  const float* beta = (const float*)d_in[3];
  float* out = (float*)d_out;

  float* ws = (float*)d_ws;
  float* G = ws;                         // 65536 f32
  float* csb = ws + 65536;               // 65536 f32 (256 blocks x 256 colsums)
  float* scale = ws + 131072;            // 128
  float* bias = ws + 131200;             // 128
  u16* Wt = (u16*)(ws + 131328);         // 512KB bf16
  u32* xb = (u32*)((char*)d_ws + (2u << 20));   // 32MB bf16-pairs at +2MB
  const size_t need = (2u << 20) + (size_t)N_ROWS * CIN * 2;
  const bool big_ws = ws_size >= need;

  // Gram partials staged in d_out (64MB of 256MB) — fully overwritten by gemm.
  float* part = (float*)d_out;

  if (big_ws) {
    gram_partial<true><<<256, 512, 0, stream>>>(x, part, csb, xb);
  } else {
    gram_partial<false><<<256, 512, 0, stream>>>(x, part, csb, xb);
  }
  gram_reduce<<<1024, 256, 0, stream>>>(part, G);
  stats_kernel<<<128, 256, 0, stream>>>(G, csb, W, gamma, beta, scale, bias);
  wtrans_kernel<<<64, 256, 0, stream>>>(W, Wt);
  if (big_ws) {
    gemm_xb<<<512, 256, 0, stream>>>((const u16*)xb, Wt, scale, bias, out);
  } else {
    gemm_fp32<<<4096, 256, 0, stream>>>(x, Wt, scale, bias, out);
  }
}

// Round 2
// 383.182 us; speedup vs baseline: 1.0397x; 1.0397x over previous
//
#include <hip/hip_runtime.h>
#include <stdint.h>

#define N_ROWS 65536
#define CIN 256
#define COUT 128

typedef __bf16 bf16x8 __attribute__((ext_vector_type(8)));
typedef float f32x4 __attribute__((ext_vector_type(4)));
typedef unsigned short u16;
typedef unsigned int u32;

__device__ __forceinline__ float truncbf(float f) {
  u32 x = __builtin_bit_cast(u32, f) & 0xFFFF0000u;
  return __builtin_bit_cast(float, x);
}
// {hi16(b), hi16(a)} -> (bf(b)<<16)|bf(a)   (truncating)
__device__ __forceinline__ u32 packbf(float a, float b) {
  return __builtin_amdgcn_perm(__builtin_bit_cast(u32, b),
                               __builtin_bit_cast(u32, a), 0x07060302u);
}
// round-to-nearest-even bf16 (for Gram partials: kills truncation bias)
__device__ __forceinline__ u32 bf_rne(float f) {
  u32 u = __builtin_bit_cast(u32, f);
  u += 0x7FFFu + ((u >> 16) & 1);
  return u >> 16;
}

__device__ __forceinline__ void async_ld16(const void* g, void* l) {
  __builtin_amdgcn_global_load_lds((const __attribute__((address_space(1))) u32*)g,
                                   (__attribute__((address_space(3))) u32*)l,
                                   16, 0, 0);
}

// ---------------------------------------------------------------------------
// Kernel 1: partial Gram over 256-row slices + per-block colsum + xb emit
//           + (blocks 0..63) W transpose -> Wt.
// 256 blocks x 512 thr -> 1 block/CU.
// Partials stored bf16-RNE, 2 rows packed per u32: 32MB total (was 64MB f32).
// x global loads double-buffered across ch iterations.
// ---------------------------------------------------------------------------
template <bool EMIT_XB>
__global__ __launch_bounds__(512, 2) void gram_partial(const float* __restrict__ x,
                                                       u32* __restrict__ part,
                                                       float* __restrict__ csb,
                                                       u32* __restrict__ xb,
                                                       const float* __restrict__ W,
                                                       u16* __restrict__ Wt) {
  __shared__ u32 xT[16 * 260];        // 16.25KB
  __shared__ float cs_s[8][256];      // 8KB
  __shared__ u16 tile[32][128];       // 8KB (wtrans tail)
  const int tid = threadIdx.x, lane = tid & 63;
  const int w = tid >> 6;
  const int wm = w >> 2, wn = w & 3;  // wave tile: 128(m) x 64(n) of G
  const int q = lane >> 4, r = lane & 15;
  const int row0 = blockIdx.x * 256;
  const int cq = tid & 63;            // channel quad: channels 4cq..4cq+3
  const int np2 = tid >> 6;           // 0..7: handles row-pairs np2, np2+8

  f32x4 acc[8][4];
  #pragma unroll
  for (int i = 0; i < 8; ++i)
    #pragma unroll
    for (int j = 0; j < 4; ++j) acc[i][j] = (f32x4){0.f, 0.f, 0.f, 0.f};
  f32x4 cs = (f32x4){0.f, 0.f, 0.f, 0.f};

  f32x4 a0, a1, b0, b1;
  {
    const int nA = row0 + np2 * 2;
    const int nB = row0 + (np2 + 8) * 2;
    a0 = *(const f32x4*)&x[(size_t)nA * CIN + 4 * cq];
    a1 = *(const f32x4*)&x[(size_t)(nA + 1) * CIN + 4 * cq];
    b0 = *(const f32x4*)&x[(size_t)nB * CIN + 4 * cq];
    b1 = *(const f32x4*)&x[(size_t)(nB + 1) * CIN + 4 * cq];
  }

  for (int ch = 0; ch < 8; ++ch) {
    const int r0 = row0 + ch * 32;
    const int nA = r0 + np2 * 2;          // rows nA, nA+1
    const int nB = r0 + (np2 + 8) * 2;    // rows nB, nB+1

    union { u32 d[4]; uint4 v; } pA, pB;
    #pragma unroll
    for (int j = 0; j < 4; ++j) {
      pA.d[j] = packbf(a0[j], a1[j]);
      pB.d[j] = packbf(b0[j], b1[j]);
      cs[j] += truncbf(a0[j]) + truncbf(a1[j]) + truncbf(b0[j]) + truncbf(b1[j]);
    }
    *(uint4*)&xT[np2 * 260 + 4 * cq] = pA.v;
    *(uint4*)&xT[(np2 + 8) * 260 + 4 * cq] = pB.v;
    if (EMIT_XB) {
      uint2 e;
      e.x = packbf(a0[0], a0[1]); e.y = packbf(a0[2], a0[3]);
      *(uint2*)&xb[(size_t)nA * 128 + 2 * cq] = e;
      e.x = packbf(a1[0], a1[1]); e.y = packbf(a1[2], a1[3]);
      *(uint2*)&xb[(size_t)(nA + 1) * 128 + 2 * cq] = e;
      e.x = packbf(b0[0], b0[1]); e.y = packbf(b0[2], b0[3]);
      *(uint2*)&xb[(size_t)nB * 128 + 2 * cq] = e;
      e.x = packbf(b1[0], b1[1]); e.y = packbf(b1[2], b1[3]);
      *(uint2*)&xb[(size_t)(nB + 1) * 128 + 2 * cq] = e;
    }
    // prefetch next ch (hides HBM latency under the MFMA phase)
    f32x4 na0, na1, nb0, nb1;
    if (ch < 7) {
      const int mA = nA + 32, mB = nB + 32;
      na0 = *(const f32x4*)&x[(size_t)mA * CIN + 4 * cq];
      na1 = *(const f32x4*)&x[(size_t)(mA + 1) * CIN + 4 * cq];
      nb0 = *(const f32x4*)&x[(size_t)mB * CIN + 4 * cq];
      nb1 = *(const f32x4*)&x[(size_t)(mB + 1) * CIN + 4 * cq];
    }
    __syncthreads();
    bf16x8 af[8], bfr[4];
    #pragma unroll
    for (int mt = 0; mt < 8; ++mt) {
      int c = wm * 128 + mt * 16 + r;
      union { u32 d[4]; bf16x8 v; } t;
      #pragma unroll
      for (int s = 0; s < 4; ++s) t.d[s] = xT[(4 * q + s) * 260 + c];
      af[mt] = t.v;
    }
    #pragma unroll
    for (int nt = 0; nt < 4; ++nt) {
      int c = wn * 64 + nt * 16 + r;
      union { u32 d[4]; bf16x8 v; } t;
      #pragma unroll
      for (int s = 0; s < 4; ++s) t.d[s] = xT[(4 * q + s) * 260 + c];
      bfr[nt] = t.v;
    }
    #pragma unroll
    for (int mt = 0; mt < 8; ++mt)
      #pragma unroll
      for (int nt = 0; nt < 4; ++nt)
        acc[mt][nt] = __builtin_amdgcn_mfma_f32_16x16x32_bf16(af[mt], bfr[nt], acc[mt][nt], 0, 0, 0);
    __syncthreads();
    if (ch < 7) { a0 = na0; a1 = na1; b0 = nb0; b1 = nb1; }
  }

  // Packed bf16 partial: part[b][rp*256+col], u32 = {row 2rp+1, row 2rp}
  u32* pb = part + (size_t)blockIdx.x * 32768;
  #pragma unroll
  for (int mt = 0; mt < 8; ++mt)
    #pragma unroll
    for (int nt = 0; nt < 4; ++nt) {
      int prow = wm * 64 + mt * 8 + q * 2;
      int col = wn * 64 + nt * 16 + r;
      pb[prow * 256 + col] = (bf_rne(acc[mt][nt][1]) << 16) | bf_rne(acc[mt][nt][0]);
      pb[(prow + 1) * 256 + col] = (bf_rne(acc[mt][nt][3]) << 16) | bf_rne(acc[mt][nt][2]);
    }

  *(f32x4*)&cs_s[np2][4 * cq] = cs;
  __syncthreads();
  if (tid < 256) {
    float s = 0.f;
    #pragma unroll
    for (int p = 0; p < 8; ++p) s += cs_s[p][tid];
    csb[(size_t)blockIdx.x * 256 + tid] = s;
  }

  // --- folded wtrans: blocks 0..63 each transpose one (k,cb) W slice ---
  if (blockIdx.x < 64) {
    const int k = blockIdx.x >> 3, cb = blockIdx.x & 7;
    #pragma unroll
    for (int i = 0; i < 2; ++i) {
      int u = tid + i * 512;
      int ci = u >> 5, d4 = (u & 31) * 4;
      float4 f = *(const float4*)&W[((size_t)k * CIN + cb * 32 + ci) * COUT + d4];
      uint2 p; p.x = packbf(f.x, f.y); p.y = packbf(f.z, f.w);
      *(uint2*)&tile[ci][d4] = p;
    }
    __syncthreads();
    {
      int d = tid >> 2, c0 = (tid & 3) * 8;
      union { u16 s[8]; uint4 u4; } p;
      #pragma unroll
      for (int j = 0; j < 8; ++j) p.s[j] = tile[c0 + j][d];
      *(uint4*)&Wt[((size_t)blockIdx.x * 128 + d) * 32 + c0] = p.u4;
    }
  }
}

// ---------------------------------------------------------------------------
// Kernel 2: reduce 256 packed-bf16 partial Grams -> G (f32).
// 512 blocks x 256 thr; each block owns 64 packed positions (=128 G entries);
// 16-way slice split per block, uint4 loads.
// ---------------------------------------------------------------------------
__global__ __launch_bounds__(256) void gram_reduce(const u32* __restrict__ part,
                                                   float* __restrict__ G) {
  __shared__ float red[16][128];
  const int t = threadIdx.x;
  const int fi = t & 15, grp = t >> 4;
  const int g0 = blockIdx.x * 64;     // packed-index base (one rp row)
  const int rp = g0 >> 8, c0 = g0 & 255;
  float fa[4] = {0.f, 0.f, 0.f, 0.f}, fb[4] = {0.f, 0.f, 0.f, 0.f};
  const u32* p = part + (size_t)(grp * 16) * 32768 + g0 + fi * 4;
  #pragma unroll
  for (int b = 0; b < 16; ++b) {
    uint4 u = *(const uint4*)(p + (size_t)b * 32768);
    const u32* uu = (const u32*)&u;
    #pragma unroll
    for (int j = 0; j < 4; ++j) {
      fa[j] += __builtin_bit_cast(float, uu[j] << 16);
      fb[j] += __builtin_bit_cast(float, uu[j] & 0xFFFF0000u);
    }
  }
  #pragma unroll
  for (int j = 0; j < 4; ++j) {
    float2 v; v.x = fa[j]; v.y = fb[j];
    *(float2*)&red[grp][(fi * 4 + j) * 2] = v;
  }
  __syncthreads();
  if (t < 128) {
    int ci = t & 63, par = t >> 6;
    float s = 0.f;
    #pragma unroll
    for (int g = 0; g < 16; ++g) s += red[g][ci * 2 + par];
    G[(size_t)(2 * rp + par) * 256 + c0 + ci] = s;
  }
}

// ---------------------------------------------------------------------------
// Kernel 3: BN scale/bias per channel d from quadratic form.
// ---------------------------------------------------------------------------
__global__ __launch_bounds__(256) void stats_kernel(const float* __restrict__ G,
                                                    const float* __restrict__ csb,
                                                    const float* __restrict__ W,
                                                    const float* __restrict__ gamma,
                                                    const float* __restrict__ beta,
                                                    float* __restrict__ scale,
                                                    float* __restrict__ bias) {
  const int d = blockIdx.x;
  const int t = threadIdx.x;
  __shared__ float wv[256][8];
  __shared__ float rr[16];
  float cst = 0.f;
  for (int b = 0; b < 256; ++b) cst += csb[b * 256 + t];
  float wt[8];
  #pragma unroll
  for (int k = 0; k < 8; ++k) wt[k] = truncbf(W[((size_t)k * CIN + t) * COUT + d]);
  #pragma unroll
  for (int k = 0; k < 8; ++k) wv[t][k] = wt[k];
  __syncthreads();

  float q = 0.f;
  for (int j = 0; j < 256; ++j) {
    float g = G[j * 256 + t];
    float dot = 0.f;
    #pragma unroll
    for (int k = 0; k < 8; ++k) dot += wv[j][k] * wt[k];
    q += g * dot;
  }
  float wsum = 0.f;
  #pragma unroll
  for (int k = 0; k < 8; ++k) wsum += wt[k];
  float m = cst * wsum;

  #pragma unroll
  for (int off = 32; off; off >>= 1) {
    q += __shfl_down(q, off, 64);
    m += __shfl_down(m, off, 64);
  }
  int wid = t >> 6;
  if ((t & 63) == 0) { rr[wid] = q; rr[wid + 8] = m; }
  __syncthreads();
  if (t == 0) {
    float qt = rr[0] + rr[1] + rr[2] + rr[3];
    float mn = rr[8] + rr[9] + rr[10] + rr[11];
    const float invM = 1.f / 524288.f;
    float mean = mn * invM;
    float var = qt * invM - mean * mean;
    float s = gamma[d] * rsqrtf(var + 1e-5f);
    scale[d] = s;
    bias[d] = beta[d] - mean * s;
  }
}

// ---------------------------------------------------------------------------
// Kernel 5 (main path): GEMM from bf16 xb, all 8 k-offsets per block.
// 512 blocks x 256 thr. A-tile 128x256 bf16 = 64KB LDS staged ONCE.
// XOR swizzle (seg ^= (row>>1)&3) on the global source (LDS dest linear for
// global_load_lds) mirrored on the ds_read side -> conflict-free b128 reads.
// ---------------------------------------------------------------------------
__global__ __launch_bounds__(256, 2) void gemm_xb(const u16* __restrict__ xb,
                                                  const u16* __restrict__ Wt,
                                                  const float* __restrict__ scale,
                                                  const float* __restrict__ bias,
                                                  float* __restrict__ out) {
  __shared__ u16 As[32768];           // 64KB: [cb][row][32] bf16, seg-swizzled
  const int tid = threadIdx.x, lane = tid & 63;
  const int w = tid >> 6, wr = w >> 1, wc = w & 1;
  const int q = lane >> 4, r = lane & 15;
  const int m0 = blockIdx.x * 128;

  #pragma unroll
  for (int i = 0; i < 16; ++i) {
    int u = tid + i * 256;            // 4096 units of 16B
    int cb = u >> 9, row = (u >> 2) & 127;
    int sseg = (u ^ (u >> 3)) & 3;    // seg ^ ((row>>1)&3)
    const u16* g = xb + (size_t)(m0 + row) * CIN + cb * 32 + sseg * 8;
    async_ld16(g, As + (size_t)u * 8);
  }

  float sv[4], bv[4];
  #pragma unroll
  for (int nt = 0; nt < 4; ++nt) {
    int col = wc * 64 + nt * 16 + r;
    sv[nt] = scale[col]; bv[nt] = bias[col];
  }

  const int boff = (wc * 64 + r) * 32 + q * 8;
  const int sw = (q ^ ((r >> 1) & 3)) * 8;   // swizzled seg offset for reads
  bf16x8 bcur[4], bnext[4];
  #pragma unroll
  for (int nt = 0; nt < 4; ++nt)
    bcur[nt] = *(const bf16x8*)&Wt[boff + nt * 512];

  __syncthreads();                    // drains the A staging too

  int j = 0;                          // j = k*8+cb
  for (int k = 0; k < 8; ++k) {
    f32x4 acc[4][4];
    #pragma unroll
    for (int i = 0; i < 4; ++i)
      #pragma unroll
      for (int jj = 0; jj < 4; ++jj) acc[i][jj] = (f32x4){0.f, 0.f, 0.f, 0.f};

    #pragma unroll
    for (int cb = 0; cb < 8; ++cb) {
      if (j < 63) {
        #pragma unroll
        for (int nt = 0; nt < 4; ++nt)
          bnext[nt] = *(const bf16x8*)&Wt[(size_t)(j + 1) * 4096 + boff + nt * 512];
      }
      bf16x8 af[4];
      #pragma unroll
      for (int mt = 0; mt < 4; ++mt)
        af[mt] = *(const bf16x8*)&As[((cb * 128) + wr * 64 + mt * 16 + r) * 32 + sw];
      #pragma unroll
      for (int mt = 0; mt < 4; ++mt)
        #pragma unroll
        for (int nt = 0; nt < 4; ++nt)
          acc[mt][nt] = __builtin_amdgcn_mfma_f32_16x16x32_bf16(af[mt], bcur[nt], acc[mt][nt], 0, 0, 0);
      if (j < 63) {
        #pragma unroll
        for (int nt = 0; nt < 4; ++nt) bcur[nt] = bnext[nt];
      }
      ++j;
    }

    const size_t obase = (size_t)k * N_ROWS + m0;
    #pragma unroll
    for (int mt = 0; mt < 4; ++mt)
      #pragma unroll
      for (int nt = 0; nt < 4; ++nt)
        #pragma unroll
        for (int i = 0; i < 4; ++i) {
          int grow = wr * 64 + mt * 16 + q * 4 + i;
          int col = wc * 64 + nt * 16 + r;
          float y = acc[mt][nt][i] * sv[nt] + bv[nt];
          y = y > 0.f ? y : 0.f;
          out[(obase + grow) * COUT + col] = y;
        }
  }
}

// ---------------------------------------------------------------------------
// Kernel 5 (fallback): GEMM from fp32 x, one k per block.
// ---------------------------------------------------------------------------
__global__ __launch_bounds__(256, 2) void gemm_fp32(const float* __restrict__ x,
                                                    const u16* __restrict__ Wt,
                                                    const float* __restrict__ scale,
                                                    const float* __restrict__ bias,
                                                    float* __restrict__ out) {
  __shared__ float Asf[4096];
  const int tid = threadIdx.x, lane = tid & 63;
  const int w = tid >> 6, wr = w >> 1, wc = w & 1;
  const int q = lane >> 4, r = lane & 15;
  const int k = blockIdx.x & 7;
  const int m0 = (blockIdx.x >> 3) * 128;

  const u16* wbase = Wt + (size_t)k * 8 * 4096;
  const int boff = (wc * 64 + r) * 32 + q * 8;

  bf16x8 bcur[4], bnext[4];
  #pragma unroll
  for (int nt = 0; nt < 4; ++nt)
    bcur[nt] = *(const bf16x8*)&wbase[boff + nt * 512];

  f32x4 acc[4][4];
  #pragma unroll
  for (int i = 0; i < 4; ++i)
    #pragma unroll
    for (int j = 0; j < 4; ++j) acc[i][j] = (f32x4){0.f, 0.f, 0.f, 0.f};

  for (int cb = 0; cb < 8; ++cb) {
    #pragma unroll
    for (int i = 0; i < 4; ++i) {
      int u = tid + i * 256;
      int row = u >> 3;
      int s = (u & 7) ^ (row & 7);
      const float* g = x + (size_t)(m0 + row) * CIN + cb * 32 + s * 4;
      async_ld16(g, Asf + (w * 64 + i * 256) * 4);
    }
    if (cb < 7) {
      #pragma unroll
      for (int nt = 0; nt < 4; ++nt)
        bnext[nt] = *(const bf16x8*)&wbase[(cb + 1) * 4096 + boff + nt * 512];
    }
    __syncthreads();
    bf16x8 af[4];
    #pragma unroll
    for (int mt = 0; mt < 4; ++mt) {
      int row = wr * 64 + mt * 16 + r;
      union { u32 d[4]; bf16x8 v; } t;
      #pragma unroll
      for (int b = 0; b < 2; ++b) {
        int unit = row * 8 + ((2 * q + b) ^ (row & 7));
        float4 f = *(const float4*)&Asf[unit * 4];
        t.d[b * 2 + 0] = packbf(f.x, f.y);
        t.d[b * 2 + 1] = packbf(f.z, f.w);
      }
      af[mt] = t.v;
    }
    #pragma unroll
    for (int mt = 0; mt < 4; ++mt)
      #pragma unroll
      for (int nt = 0; nt < 4; ++nt)
        acc[mt][nt] = __builtin_amdgcn_mfma_f32_16x16x32_bf16(af[mt], bcur[nt], acc[mt][nt], 0, 0, 0);
    __syncthreads();
    if (cb < 7) {
      #pragma unroll
      for (int nt = 0; nt < 4; ++nt) bcur[nt] = bnext[nt];
    }
  }

  float sv[4], bv[4];
  #pragma unroll
  for (int nt = 0; nt < 4; ++nt) {
    int col = wc * 64 + nt * 16 + r;
    sv[nt] = scale[col]; bv[nt] = bias[col];
  }
  const size_t obase = (size_t)k * N_ROWS + m0;
  #pragma unroll
  for (int mt = 0; mt < 4; ++mt)
    #pragma unroll
    for (int nt = 0; nt < 4; ++nt)
      #pragma unroll
      for (int i = 0; i < 4; ++i) {
        int grow = wr * 64 + mt * 16 + q * 4 + i;
        int col = wc * 64 + nt * 16 + r;
        float y = acc[mt][nt][i] * sv[nt] + bv[nt];
        y = y > 0.f ? y : 0.f;
        out[(obase + grow) * COUT + col] = y;
      }
}

extern "C" void kernel_launch(void* const* d_in, const int* in_sizes, int n_in,
                              void* d_out, int out_size, void* d_ws, size_t ws_size,
                              hipStream_t stream) {
  const float* x = (const float*)d_in[0];
  const float* W = (const float*)d_in[1];
  const float* gamma = (const float*)d_in[2];
  const float* beta = (const float*)d_in[3];
  float* out = (float*)d_out;

  float* ws = (float*)d_ws;
  float* G = ws;                         // 65536 f32
  float* csb = ws + 65536;               // 65536 f32 (256 blocks x 256 colsums)
  float* scale = ws + 131072;            // 128
  float* bias = ws + 131200;             // 128
  u16* Wt = (u16*)(ws + 131328);         // 512KB bf16
  u32* xb = (u32*)((char*)d_ws + (2u << 20));   // 32MB bf16-pairs at +2MB
  const size_t need = (2u << 20) + (size_t)N_ROWS * CIN * 2;
  const bool big_ws = ws_size >= need;

  // Packed bf16 Gram partials staged in d_out (32MB of 256MB) — fully
  // overwritten by the gemm afterwards.
  u32* part = (u32*)d_out;

  if (big_ws) {
    gram_partial<true><<<256, 512, 0, stream>>>(x, part, csb, xb, W, Wt);
  } else {
    gram_partial<false><<<256, 512, 0, stream>>>(x, part, csb, xb, W, Wt);
  }
  gram_reduce<<<512, 256, 0, stream>>>(part, G);
  stats_kernel<<<128, 256, 0, stream>>>(G, csb, W, gamma, beta, scale, bias);
  if (big_ws) {
    gemm_xb<<<512, 256, 0, stream>>>((const u16*)xb, Wt, scale, bias, out);
  } else {
    gemm_fp32<<<4096, 256, 0, stream>>>(x, Wt, scale, bias, out);
  }
}

// Round 3
// 379.609 us; speedup vs baseline: 1.0495x; 1.0094x over previous
//
#include <hip/hip_runtime.h>
#include <stdint.h>

#define N_ROWS 65536
#define CIN 256
#define COUT 128

typedef __bf16 bf16x8 __attribute__((ext_vector_type(8)));
typedef float f32x4 __attribute__((ext_vector_type(4)));
typedef unsigned short u16;
typedef unsigned int u32;

__device__ __forceinline__ float truncbf(float f) {
  u32 x = __builtin_bit_cast(u32, f) & 0xFFFF0000u;
  return __builtin_bit_cast(float, x);
}
// {hi16(b), hi16(a)} -> (bf(b)<<16)|bf(a)   (truncating)
__device__ __forceinline__ u32 packbf(float a, float b) {
  return __builtin_amdgcn_perm(__builtin_bit_cast(u32, b),
                               __builtin_bit_cast(u32, a), 0x07060302u);
}
// round-to-nearest-even bf16 (for Gram partials: kills truncation bias)
__device__ __forceinline__ u32 bf_rne(float f) {
  u32 u = __builtin_bit_cast(u32, f);
  u += 0x7FFFu + ((u >> 16) & 1);
  return u >> 16;
}

// ---------------------------------------------------------------------------
// Kernel 1: partial Gram over 512-row slices + per-block colsum
//           + (blocks 0..63) W transpose -> Wt.
// 128 blocks x 512 thr. Partials bf16-RNE packed 2 rows/u32: 16MB total.
// x global loads double-buffered across the 16 ch iterations.
// ---------------------------------------------------------------------------
__global__ __launch_bounds__(512, 2) void gram_partial(const float* __restrict__ x,
                                                       u32* __restrict__ part,
                                                       float* __restrict__ csb,
                                                       const float* __restrict__ W,
                                                       u16* __restrict__ Wt) {
  __shared__ u32 xT[16 * 260];        // 16.25KB
  __shared__ float cs_s[8][256];      // 8KB
  __shared__ u16 tile[32][128];       // 8KB (wtrans tail)
  const int tid = threadIdx.x, lane = tid & 63;
  const int w = tid >> 6;
  const int wm = w >> 2, wn = w & 3;  // wave tile: 128(m) x 64(n) of G
  const int q = lane >> 4, r = lane & 15;
  const int row0 = blockIdx.x * 512;
  const int cq = tid & 63;            // channel quad: channels 4cq..4cq+3
  const int np2 = tid >> 6;           // 0..7: handles row-pairs np2, np2+8

  f32x4 acc[8][4];
  #pragma unroll
  for (int i = 0; i < 8; ++i)
    #pragma unroll
    for (int j = 0; j < 4; ++j) acc[i][j] = (f32x4){0.f, 0.f, 0.f, 0.f};
  f32x4 cs = (f32x4){0.f, 0.f, 0.f, 0.f};

  f32x4 a0, a1, b0, b1;
  {
    const int nA = row0 + np2 * 2;
    const int nB = row0 + (np2 + 8) * 2;
    a0 = *(const f32x4*)&x[(size_t)nA * CIN + 4 * cq];
    a1 = *(const f32x4*)&x[(size_t)(nA + 1) * CIN + 4 * cq];
    b0 = *(const f32x4*)&x[(size_t)nB * CIN + 4 * cq];
    b1 = *(const f32x4*)&x[(size_t)(nB + 1) * CIN + 4 * cq];
  }

  for (int ch = 0; ch < 16; ++ch) {
    union { u32 d[4]; uint4 v; } pA, pB;
    #pragma unroll
    for (int j = 0; j < 4; ++j) {
      pA.d[j] = packbf(a0[j], a1[j]);
      pB.d[j] = packbf(b0[j], b1[j]);
      cs[j] += truncbf(a0[j]) + truncbf(a1[j]) + truncbf(b0[j]) + truncbf(b1[j]);
    }
    *(uint4*)&xT[np2 * 260 + 4 * cq] = pA.v;
    *(uint4*)&xT[(np2 + 8) * 260 + 4 * cq] = pB.v;

    // prefetch next ch slice (hides HBM latency under the MFMA phase)
    f32x4 na0, na1, nb0, nb1;
    if (ch < 15) {
      const int r0n = row0 + (ch + 1) * 32;
      const int mA = r0n + np2 * 2;
      const int mB = r0n + (np2 + 8) * 2;
      na0 = *(const f32x4*)&x[(size_t)mA * CIN + 4 * cq];
      na1 = *(const f32x4*)&x[(size_t)(mA + 1) * CIN + 4 * cq];
      nb0 = *(const f32x4*)&x[(size_t)mB * CIN + 4 * cq];
      nb1 = *(const f32x4*)&x[(size_t)(mB + 1) * CIN + 4 * cq];
    }
    __syncthreads();
    bf16x8 af[8], bfr[4];
    #pragma unroll
    for (int mt = 0; mt < 8; ++mt) {
      int c = wm * 128 + mt * 16 + r;
      union { u32 d[4]; bf16x8 v; } t;
      #pragma unroll
      for (int s = 0; s < 4; ++s) t.d[s] = xT[(4 * q + s) * 260 + c];
      af[mt] = t.v;
    }
    #pragma unroll
    for (int nt = 0; nt < 4; ++nt) {
      int c = wn * 64 + nt * 16 + r;
      union { u32 d[4]; bf16x8 v; } t;
      #pragma unroll
      for (int s = 0; s < 4; ++s) t.d[s] = xT[(4 * q + s) * 260 + c];
      bfr[nt] = t.v;
    }
    #pragma unroll
    for (int mt = 0; mt < 8; ++mt)
      #pragma unroll
      for (int nt = 0; nt < 4; ++nt)
        acc[mt][nt] = __builtin_amdgcn_mfma_f32_16x16x32_bf16(af[mt], bfr[nt], acc[mt][nt], 0, 0, 0);
    __syncthreads();
    if (ch < 15) { a0 = na0; a1 = na1; b0 = nb0; b1 = nb1; }
  }

  // Packed bf16 partial: part[b][rp*256+col], u32 = {row 2rp+1, row 2rp}
  u32* pb = part + (size_t)blockIdx.x * 32768;
  #pragma unroll
  for (int mt = 0; mt < 8; ++mt)
    #pragma unroll
    for (int nt = 0; nt < 4; ++nt) {
      int prow = wm * 64 + mt * 8 + q * 2;
      int col = wn * 64 + nt * 16 + r;
      pb[prow * 256 + col] = (bf_rne(acc[mt][nt][1]) << 16) | bf_rne(acc[mt][nt][0]);
      pb[(prow + 1) * 256 + col] = (bf_rne(acc[mt][nt][3]) << 16) | bf_rne(acc[mt][nt][2]);
    }

  *(f32x4*)&cs_s[np2][4 * cq] = cs;
  __syncthreads();
  if (tid < 256) {
    float s = 0.f;
    #pragma unroll
    for (int p = 0; p < 8; ++p) s += cs_s[p][tid];
    csb[(size_t)blockIdx.x * 256 + tid] = s;
  }

  // --- folded wtrans: blocks 0..63 each transpose one (k,cb) W slice ---
  if (blockIdx.x < 64) {
    const int k = blockIdx.x >> 3, cb = blockIdx.x & 7;
    #pragma unroll
    for (int i = 0; i < 2; ++i) {
      int u = tid + i * 512;
      int ci = u >> 5, d4 = (u & 31) * 4;
      float4 f = *(const float4*)&W[((size_t)k * CIN + cb * 32 + ci) * COUT + d4];
      uint2 p; p.x = packbf(f.x, f.y); p.y = packbf(f.z, f.w);
      *(uint2*)&tile[ci][d4] = p;
    }
    __syncthreads();
    {
      int d = tid >> 2, c0 = (tid & 3) * 8;
      union { u16 s[8]; uint4 u4; } p;
      #pragma unroll
      for (int j = 0; j < 8; ++j) p.s[j] = tile[c0 + j][d];
      *(uint4*)&Wt[((size_t)blockIdx.x * 128 + d) * 32 + c0] = p.u4;
    }
  }
}

// ---------------------------------------------------------------------------
// Kernel 2: reduce 128 packed-bf16 partial Grams -> G (f32).
// 512 blocks x 256 thr; each block owns 64 packed positions (=128 G entries);
// 16-way slice split (8 partials each), uint4 loads.
// ---------------------------------------------------------------------------
__global__ __launch_bounds__(256) void gram_reduce(const u32* __restrict__ part,
                                                   float* __restrict__ G) {
  __shared__ float red[16][128];
  const int t = threadIdx.x;
  const int fi = t & 15, grp = t >> 4;
  const int g0 = blockIdx.x * 64;     // packed-index base (one rp row)
  const int rp = g0 >> 8, c0 = g0 & 255;
  float fa[4] = {0.f, 0.f, 0.f, 0.f}, fb[4] = {0.f, 0.f, 0.f, 0.f};
  const u32* p = part + (size_t)(grp * 8) * 32768 + g0 + fi * 4;
  #pragma unroll
  for (int b = 0; b < 8; ++b) {
    uint4 u = *(const uint4*)(p + (size_t)b * 32768);
    const u32* uu = (const u32*)&u;
    #pragma unroll
    for (int j = 0; j < 4; ++j) {
      fa[j] += __builtin_bit_cast(float, uu[j] << 16);
      fb[j] += __builtin_bit_cast(float, uu[j] & 0xFFFF0000u);
    }
  }
  #pragma unroll
  for (int j = 0; j < 4; ++j) {
    float2 v; v.x = fa[j]; v.y = fb[j];
    *(float2*)&red[grp][(fi * 4 + j) * 2] = v;
  }
  __syncthreads();
  if (t < 128) {
    int ci = t & 63, par = t >> 6;
    float s = 0.f;
    #pragma unroll
    for (int g = 0; g < 16; ++g) s += red[g][ci * 2 + par];
    G[(size_t)(2 * rp + par) * 256 + c0 + ci] = s;
  }
}

// ---------------------------------------------------------------------------
// Kernel 3: BN scale/bias per channel d from quadratic form.
// ---------------------------------------------------------------------------
__global__ __launch_bounds__(256) void stats_kernel(const float* __restrict__ G,
                                                    const float* __restrict__ csb,
                                                    const float* __restrict__ W,
                                                    const float* __restrict__ gamma,
                                                    const float* __restrict__ beta,
                                                    float* __restrict__ scale,
                                                    float* __restrict__ bias) {
  const int d = blockIdx.x;
  const int t = threadIdx.x;
  __shared__ float wv[256][8];
  __shared__ float rr[16];
  float cst = 0.f;
  for (int b = 0; b < 128; ++b) cst += csb[b * 256 + t];
  float wt[8];
  #pragma unroll
  for (int k = 0; k < 8; ++k) wt[k] = truncbf(W[((size_t)k * CIN + t) * COUT + d]);
  #pragma unroll
  for (int k = 0; k < 8; ++k) wv[t][k] = wt[k];
  __syncthreads();

  float q = 0.f;
  for (int j = 0; j < 256; ++j) {
    float g = G[j * 256 + t];
    float dot = 0.f;
    #pragma unroll
    for (int k = 0; k < 8; ++k) dot += wv[j][k] * wt[k];
    q += g * dot;
  }
  float wsum = 0.f;
  #pragma unroll
  for (int k = 0; k < 8; ++k) wsum += wt[k];
  float m = cst * wsum;

  #pragma unroll
  for (int off = 32; off; off >>= 1) {
    q += __shfl_down(q, off, 64);
    m += __shfl_down(m, off, 64);
  }
  int wid = t >> 6;
  if ((t & 63) == 0) { rr[wid] = q; rr[wid + 8] = m; }
  __syncthreads();
  if (t == 0) {
    float qt = rr[0] + rr[1] + rr[2] + rr[3];
    float mn = rr[8] + rr[9] + rr[10] + rr[11];
    const float invM = 1.f / 524288.f;
    float mean = mn * invM;
    float var = qt * invM - mean * mean;
    float s = gamma[d] * rsqrtf(var + 1e-5f);
    scale[d] = s;
    bias[d] = beta[d] - mean * s;
  }
}

// ---------------------------------------------------------------------------
// Kernel 4: GEMM reading fp32 x directly (no xb round-trip), all 8 k-offsets
// per block. 512 blocks x 256 thr. A-tile 128x256 -> bf16 in LDS (64KB),
// reg-staged once: same seg-swizzled As layout as before (write addr linear
// in unit u, CONTENT seg pre-swizzled), so the inner loop's swizzled b128
// reads stay conflict-free. Numerics identical to the xb path (same
// truncating pack).
// ---------------------------------------------------------------------------
__global__ __launch_bounds__(256, 2) void gemm_x(const float* __restrict__ x,
                                                 const u16* __restrict__ Wt,
                                                 const float* __restrict__ scale,
                                                 const float* __restrict__ bias,
                                                 float* __restrict__ out) {
  __shared__ u16 As[32768];           // 64KB: [cb][row][32] bf16, seg-swizzled
  const int tid = threadIdx.x, lane = tid & 63;
  const int w = tid >> 6, wr = w >> 1, wc = w & 1;
  const int q = lane >> 4, r = lane & 15;
  const int m0 = blockIdx.x * 128;

  #pragma unroll
  for (int i = 0; i < 16; ++i) {
    int u = tid + i * 256;            // 4096 units of 16B (8 bf16)
    int cb = u >> 9, row = (u >> 2) & 127;
    int sseg = (u ^ (u >> 3)) & 3;    // seg ^ ((row>>1)&3)
    const float* g = &x[(size_t)(m0 + row) * CIN + cb * 32 + sseg * 8];
    f32x4 f0 = *(const f32x4*)g;
    f32x4 f1 = *(const f32x4*)(g + 4);
    union { u32 d[4]; uint4 v; } t4;
    t4.d[0] = packbf(f0[0], f0[1]);
    t4.d[1] = packbf(f0[2], f0[3]);
    t4.d[2] = packbf(f1[0], f1[1]);
    t4.d[3] = packbf(f1[2], f1[3]);
    *(uint4*)&As[(size_t)u * 8] = t4.v;
  }

  float sv[4], bv[4];
  #pragma unroll
  for (int nt = 0; nt < 4; ++nt) {
    int col = wc * 64 + nt * 16 + r;
    sv[nt] = scale[col]; bv[nt] = bias[col];
  }

  const int boff = (wc * 64 + r) * 32 + q * 8;
  const int sw = (q ^ ((r >> 1) & 3)) * 8;   // swizzled seg offset for reads
  bf16x8 bcur[4], bnext[4];
  #pragma unroll
  for (int nt = 0; nt < 4; ++nt)
    bcur[nt] = *(const bf16x8*)&Wt[boff + nt * 512];

  __syncthreads();

  int j = 0;                          // j = k*8+cb
  for (int k = 0; k < 8; ++k) {
    f32x4 acc[4][4];
    #pragma unroll
    for (int i = 0; i < 4; ++i)
      #pragma unroll
      for (int jj = 0; jj < 4; ++jj) acc[i][jj] = (f32x4){0.f, 0.f, 0.f, 0.f};

    #pragma unroll
    for (int cb = 0; cb < 8; ++cb) {
      if (j < 63) {
        #pragma unroll
        for (int nt = 0; nt < 4; ++nt)
          bnext[nt] = *(const bf16x8*)&Wt[(size_t)(j + 1) * 4096 + boff + nt * 512];
      }
      bf16x8 af[4];
      #pragma unroll
      for (int mt = 0; mt < 4; ++mt)
        af[mt] = *(const bf16x8*)&As[((cb * 128) + wr * 64 + mt * 16 + r) * 32 + sw];
      #pragma unroll
      for (int mt = 0; mt < 4; ++mt)
        #pragma unroll
        for (int nt = 0; nt < 4; ++nt)
          acc[mt][nt] = __builtin_amdgcn_mfma_f32_16x16x32_bf16(af[mt], bcur[nt], acc[mt][nt], 0, 0, 0);
      if (j < 63) {
        #pragma unroll
        for (int nt = 0; nt < 4; ++nt) bcur[nt] = bnext[nt];
      }
      ++j;
    }

    const size_t obase = (size_t)k * N_ROWS + m0;
    #pragma unroll
    for (int mt = 0; mt < 4; ++mt)
      #pragma unroll
      for (int nt = 0; nt < 4; ++nt)
        #pragma unroll
        for (int i = 0; i < 4; ++i) {
          int grow = wr * 64 + mt * 16 + q * 4 + i;
          int col = wc * 64 + nt * 16 + r;
          float y = acc[mt][nt][i] * sv[nt] + bv[nt];
          y = y > 0.f ? y : 0.f;
          out[(obase + grow) * COUT + col] = y;
        }
  }
}

extern "C" void kernel_launch(void* const* d_in, const int* in_sizes, int n_in,
                              void* d_out, int out_size, void* d_ws, size_t ws_size,
                              hipStream_t stream) {
  const float* x = (const float*)d_in[0];
  const float* W = (const float*)d_in[1];
  const float* gamma = (const float*)d_in[2];
  const float* beta = (const float*)d_in[3];
  float* out = (float*)d_out;

  float* ws = (float*)d_ws;
  float* G = ws;                         // 65536 f32
  float* csb = ws + 65536;               // 32768 f32 (128 blocks x 256)
  float* scale = ws + 98304;             // 128
  float* bias = ws + 98432;              // 128
  u16* Wt = (u16*)(ws + 98560);          // 512KB bf16

  // Packed bf16 Gram partials staged in d_out (16MB of 256MB) — fully
  // overwritten by the gemm afterwards.
  u32* part = (u32*)d_out;

  gram_partial<<<128, 512, 0, stream>>>(x, part, csb, W, Wt);
  gram_reduce<<<512, 256, 0, stream>>>(part, G);
  stats_kernel<<<128, 256, 0, stream>>>(G, csb, W, gamma, beta, scale, bias);
  gemm_x<<<512, 256, 0, stream>>>(x, Wt, scale, bias, out);
}